// Round 1
// baseline (281.916 us; speedup 1.0000x reference)
//
#include <hip/hip_runtime.h>
#include <hip/hip_bf16.h>

// B=4, S=1024, D=1024, H=16, DH=64. Softmax over HEADS (per (i,j)), per reference.

using f32x4  = __attribute__((ext_vector_type(4))) float;
using bf16x8 = __attribute__((ext_vector_type(8))) short;

__device__ inline unsigned short f2b(float f){
    unsigned u = __float_as_uint(f);
    unsigned r = (u + 0x7fffu + ((u >> 16) & 1u)) >> 16;
    return (unsigned short)r;
}

#define GLL16(gp, lp) __builtin_amdgcn_global_load_lds( \
    (const __attribute__((address_space(1))) void*)(gp), \
    (__attribute__((address_space(3))) void*)(lp), 16, 0, 0)

// ---------------- convert q,k,v f32 -> bf16, contiguous [3][4096][1024] -------
__global__ __launch_bounds__(256) void convert_qkv(
    const float* __restrict__ q, const float* __restrict__ k, const float* __restrict__ v,
    unsigned short* __restrict__ dst)
{
    const long gid = (long)blockIdx.x * 256 + threadIdx.x;   // group of 4 floats
    const int  t   = (int)(gid >> 20);                       // 1048576 groups per tensor
    const long off = (gid & 1048575) << 2;
    const float* src = (t == 0) ? q : (t == 1) ? k : v;
    const float4 x = *(const float4*)(src + off);
    ushort4 o;
    o.x = f2b(x.x); o.y = f2b(x.y); o.z = f2b(x.z); o.w = f2b(x.w);
    *(ushort4*)(dst + (long)t * 4194304 + off) = o;
}

// ---------------- transpose+convert W f32 [k][n] -> bf16 [n][k] ---------------
__global__ __launch_bounds__(256) void wtrans(
    const float* __restrict__ w0, const float* __restrict__ w1,
    const float* __restrict__ w2, const float* __restrict__ w3,
    unsigned short* __restrict__ out)
{
    const float* W = (blockIdx.z == 0) ? w0 : (blockIdx.z == 1) ? w1 : (blockIdx.z == 2) ? w2 : w3;
    unsigned short* O = out + (long)blockIdx.z * 1048576;
    __shared__ float t[32][33];
    const int n0 = blockIdx.x * 32, k0 = blockIdx.y * 32;
    const int tx = threadIdx.x, ty = threadIdx.y;   // (32,8)
    #pragma unroll
    for (int i = 0; i < 4; i++)
        t[ty + 8*i][tx] = W[(long)(k0 + ty + 8*i) * 1024 + n0 + tx];
    __syncthreads();
    #pragma unroll
    for (int i = 0; i < 4; i++)
        O[(long)(n0 + ty + 8*i) * 1024 + k0 + tx] = f2b(t[tx][ty + 8*i]);
}

// ---------------- transpose V bf16 [b*1024+s][d] -> Vt [b][d][s] --------------
__global__ __launch_bounds__(256) void vtrans(
    const unsigned short* __restrict__ V, unsigned short* __restrict__ Vt)
{
    const int b = blockIdx.z;
    __shared__ unsigned short t[32][33];
    const int s0 = blockIdx.x * 32, d0 = blockIdx.y * 32;
    const int tx = threadIdx.x, ty = threadIdx.y;
    #pragma unroll
    for (int i = 0; i < 4; i++)
        t[ty + 8*i][tx] = V[(long)(b*1024 + s0 + ty + 8*i) * 1024 + d0 + tx];
    __syncthreads();
    #pragma unroll
    for (int i = 0; i < 4; i++)
        Vt[(long)b * 1048576 + (long)(d0 + ty + 8*i) * 1024 + s0 + tx] = t[tx][ty + 8*i];
}

// ---------------- GEMM: C[M][N] = A[M][K](bf16) @ BT[N][K](bf16)^T + bias -----
// m97 structure: 128x128 tile, BK=32, 4 waves, global_load_lds(16B) staging.
template<int OUTF32>
__global__ __launch_bounds__(256) void gemm_bias(
    const unsigned short* __restrict__ A,
    const unsigned short* __restrict__ BT,
    const float* __restrict__ bias,
    void* __restrict__ Cout, int M, int N, int K)
{
    __shared__ unsigned short As[128 * 32];
    __shared__ unsigned short Bs[128 * 32];
    const int tid  = threadIdx.x;
    const int wave = tid >> 6, lane = tid & 63;
    const int l15  = lane & 15, l4 = lane >> 4;
    const int wr   = wave >> 1, wc = wave & 1;
    const long rowBase = (long)blockIdx.x * 128;
    const long colBase = (long)blockIdx.y * 128;

    f32x4 acc[4][4];
    #pragma unroll
    for (int m = 0; m < 4; m++)
        #pragma unroll
        for (int n = 0; n < 4; n++)
            acc[m][n] = (f32x4){0.f, 0.f, 0.f, 0.f};

    const int c0    = wave * 2;
    const int srow0 = c0 * 16 + (lane >> 2);
    const int srow1 = srow0 + 16;
    const int skk   = (lane & 3) * 8;

    for (int k0 = 0; k0 < K; k0 += 32) {
        GLL16(A  + (rowBase + srow0) * K + k0 + skk, As + c0 * 512);
        GLL16(A  + (rowBase + srow1) * K + k0 + skk, As + (c0 + 1) * 512);
        GLL16(BT + (colBase + srow0) * K + k0 + skk, Bs + c0 * 512);
        GLL16(BT + (colBase + srow1) * K + k0 + skk, Bs + (c0 + 1) * 512);
        __syncthreads();
        bf16x8 af[4], bfr[4];
        #pragma unroll
        for (int m = 0; m < 4; m++)
            af[m] = *(const bf16x8*)(As + (wr*64 + m*16 + l15) * 32 + l4 * 8);
        #pragma unroll
        for (int n = 0; n < 4; n++)
            bfr[n] = *(const bf16x8*)(Bs + (wc*64 + n*16 + l15) * 32 + l4 * 8);
        #pragma unroll
        for (int m = 0; m < 4; m++)
            #pragma unroll
            for (int n = 0; n < 4; n++)
                acc[m][n] = __builtin_amdgcn_mfma_f32_16x16x32_bf16(af[m], bfr[n], acc[m][n], 0, 0, 0);
        __syncthreads();
    }

    #pragma unroll
    for (int m = 0; m < 4; m++) {
        const long row = rowBase + wr*64 + m*16 + l4*4;
        #pragma unroll
        for (int n = 0; n < 4; n++) {
            const long col = colBase + wc*64 + n*16 + l15;
            const float bv = bias[col];
            #pragma unroll
            for (int r = 0; r < 4; r++) {
                const float vv = acc[m][n][r] + bv;
                if (OUTF32) ((float*)Cout)[(row + r) * N + col] = vv;
                else        ((unsigned short*)Cout)[(row + r) * N + col] = f2b(vv);
            }
        }
    }
}

// ---------------- fused attention: per (b, 16-row i-tile) ---------------------
// scores (all 16 heads) -> head-softmax per (i,j) -> PV accumulate.
__global__ __launch_bounds__(512) void attn_fused(
    const unsigned short* __restrict__ Q,    // [4096][1024]
    const unsigned short* __restrict__ Kg_,  // [4096][1024]
    const unsigned short* __restrict__ Vt,   // [4][1024(d)][1024(s)]
    const int* __restrict__ mask,            // [1024*1024]
    unsigned short* __restrict__ X)          // [4096][1024]
{
    __shared__ float s_lds[16 * 32 * 17];          // [(i*32+j)*17 + h]
    __shared__ unsigned short p_lds[16 * 16 * 40]; // [h*640 + i*40 + j]
    const int tid  = threadIdx.x;
    const int wave = tid >> 6, lane = tid & 63;
    const int l15  = lane & 15, l4 = lane >> 4;
    const int b  = blockIdx.x >> 6;
    const int i0 = (blockIdx.x & 63) << 4;

    bf16x8 qf[2][2];
    {
        const unsigned short* Qrow = Q + (long)(b*1024 + i0 + l15) * 1024;
        #pragma unroll
        for (int hh = 0; hh < 2; hh++) {
            const int h = wave*2 + hh;
            qf[hh][0] = *(const bf16x8*)(Qrow + h*64 + l4*8);
            qf[hh][1] = *(const bf16x8*)(Qrow + h*64 + 32 + l4*8);
        }
    }
    f32x4 acc[2][4];
    #pragma unroll
    for (int a = 0; a < 2; a++)
        #pragma unroll
        for (int n = 0; n < 4; n++)
            acc[a][n] = (f32x4){0.f, 0.f, 0.f, 0.f};

    const unsigned short* Kb = Kg_ + (long)b * 1048576;
    const unsigned short* Vb = Vt  + (long)b * 1048576;

    for (int j0 = 0; j0 < 1024; j0 += 32) {
        // ---- scores: 2 heads per wave, 2 j-subtiles, K=64 (2 MFMA) ----
        #pragma unroll
        for (int hh = 0; hh < 2; hh++) {
            const int h = wave*2 + hh;
            #pragma unroll
            for (int n = 0; n < 2; n++) {
                const unsigned short* Krow = Kb + (long)(j0 + n*16 + l15) * 1024 + h*64;
                bf16x8 kf0 = *(const bf16x8*)(Krow + l4*8);
                bf16x8 kf1 = *(const bf16x8*)(Krow + 32 + l4*8);
                f32x4 s = (f32x4){0.f, 0.f, 0.f, 0.f};
                s = __builtin_amdgcn_mfma_f32_16x16x32_bf16(qf[hh][0], kf0, s, 0, 0, 0);
                s = __builtin_amdgcn_mfma_f32_16x16x32_bf16(qf[hh][1], kf1, s, 0, 0, 0);
                #pragma unroll
                for (int r = 0; r < 4; r++)
                    s_lds[((l4*4 + r)*32 + n*16 + l15) * 17 + h] = s[r];
            }
        }
        __syncthreads();
        // ---- head-softmax: one thread per (i,j) ----
        {
            const int i = tid >> 5, j = tid & 31;
            float* sp = s_lds + (long)tid * 17;
            const int mk = mask[(i0 + i) * 1024 + j0 + j];
            float sc[16];
            float mx = -1e30f;
            #pragma unroll
            for (int h = 0; h < 16; h++) {
                float vv = sp[h] * 0.125f;
                if (mk == 0) vv = -__builtin_inff();
                sc[h] = vv;
                mx = fmaxf(mx, vv);
            }
            float Z = 0.f;
            #pragma unroll
            for (int h = 0; h < 16; h++) {
                const float e = __expf(sc[h] - mx);
                sc[h] = e; Z += e;
            }
            const float inv = 1.f / Z;
            #pragma unroll
            for (int h = 0; h < 16; h++)
                p_lds[h*640 + i*40 + j] = f2b(sc[h] * inv);
        }
        __syncthreads();
        // ---- PV: acc[i][dv] += P[i][j] * V[j][dv] per head ----
        #pragma unroll
        for (int hh = 0; hh < 2; hh++) {
            const int h = wave*2 + hh;
            bf16x8 pf = *(const bf16x8*)(p_lds + h*640 + l15*40 + l4*8);
            #pragma unroll
            for (int n = 0; n < 4; n++) {
                bf16x8 vf = *(const bf16x8*)(Vb + (long)(h*64 + n*16 + l15) * 1024 + j0 + l4*8);
                acc[hh][n] = __builtin_amdgcn_mfma_f32_16x16x32_bf16(pf, vf, acc[hh][n], 0, 0, 0);
            }
        }
        __syncthreads();
    }
    #pragma unroll
    for (int hh = 0; hh < 2; hh++) {
        const int h = wave*2 + hh;
        #pragma unroll
        for (int n = 0; n < 4; n++)
            #pragma unroll
            for (int r = 0; r < 4; r++) {
                const long row = b*1024 + i0 + l4*4 + r;
                X[row * 1024 + h*64 + n*16 + l15] = f2b(acc[hh][n][r]);
            }
    }
}

extern "C" void kernel_launch(void* const* d_in, const int* in_sizes, int n_in,
                              void* d_out, int out_size, void* d_ws, size_t ws_size,
                              hipStream_t stream)
{
    const float* q    = (const float*)d_in[0];
    const float* k    = (const float*)d_in[1];
    const float* v    = (const float*)d_in[2];
    const int*   mask = (const int*)  d_in[3];
    const float* Wq   = (const float*)d_in[4];
    const float* bq   = (const float*)d_in[5];
    const float* Wk   = (const float*)d_in[6];
    const float* bk   = (const float*)d_in[7];
    const float* Wv   = (const float*)d_in[8];
    const float* bv   = (const float*)d_in[9];
    const float* Wo   = (const float*)d_in[10];
    const float* bo   = (const float*)d_in[11];

    unsigned short* ws = (unsigned short*)d_ws;
    const long MS = 1048576;              // 1M bf16 elements = 2MB
    unsigned short* WT  = ws;             // 4 transposed weights   [0,8MB)
    unsigned short* Xq  = ws + 4*MS;      // bf16 query -> later Vt [8,16MB)
    unsigned short* Xk  = ws + 8*MS;      // bf16 key  -> later Xat [16,24MB)
    unsigned short* Xv  = ws + 12*MS;     // bf16 value             [24,32MB)
    unsigned short* Qm  = ws + 16*MS;     // Q projection           [32,40MB)
    unsigned short* Km  = ws + 20*MS;     // K projection           [40,48MB)
    unsigned short* Vm  = ws + 24*MS;     // V projection           [48,56MB)
    unsigned short* Vtm = Xq;             // V transposed (Xq dead after Q-GEMM)
    unsigned short* Xat = Xk;             // attention out (Xk dead after K-GEMM)

    convert_qkv<<<12288, 256, 0, stream>>>(q, k, v, Xq);
    wtrans<<<dim3(32, 32, 4), dim3(32, 8), 0, stream>>>(Wq, Wk, Wv, Wo, WT);
    gemm_bias<0><<<dim3(32, 8), 256, 0, stream>>>(Xq, WT,        bq, Qm, 4096, 1024, 1024);
    gemm_bias<0><<<dim3(32, 8), 256, 0, stream>>>(Xk, WT + MS,   bk, Km, 4096, 1024, 1024);
    gemm_bias<0><<<dim3(32, 8), 256, 0, stream>>>(Xv, WT + 2*MS, bv, Vm, 4096, 1024, 1024);
    vtrans<<<dim3(32, 32, 4), dim3(32, 8), 0, stream>>>(Vm, Vtm);
    attn_fused<<<256, 512, 0, stream>>>(Qm, Km, Vtm, mask, Xat);
    gemm_bias<1><<<dim3(32, 8), 256, 0, stream>>>(Xat, WT + 3*MS, bo, d_out, 4096, 1024, 1024);
}